// Round 7
// baseline (554.809 us; speedup 1.0000x reference)
//
#include <hip/hip_runtime.h>
#include <hip/hip_bf16.h>
#include <math.h>

#define NTOK 49
#define NH 12
#define HD 32
#define CDIM 384
#define NWIN 64
#define BWIN 2048

typedef __bf16 bf16x8 __attribute__((ext_vector_type(8)));
typedef __bf16 bf16x4 __attribute__((ext_vector_type(4)));
typedef float f32x4 __attribute__((ext_vector_type(4)));

// ---------------- fp32 -> bf16 convert (weights) ----------------
__global__ void cvt_f32_bf16(const float* __restrict__ src, __bf16* __restrict__ dst, int n8) {
    int i = blockIdx.x * blockDim.x + threadIdx.x;
    if (i >= n8) return;
    f32x4 a = *(const f32x4*)(src + (size_t)i * 8);
    f32x4 b = *(const f32x4*)(src + (size_t)i * 8 + 4);
    bf16x8 o;
#pragma unroll
    for (int e = 0; e < 4; ++e) { o[e] = (__bf16)a[e]; o[e + 4] = (__bf16)b[e]; }
    *(bf16x8*)(dst + (size_t)i * 8) = o;
}

// ---------------- CPB MLP: bias_tab[169][12] ----------------
__global__ void cpb_mlp_kernel(const float* __restrict__ w1, const float* __restrict__ b1,
                               const float* __restrict__ w2, float* __restrict__ bias_tab) {
    int t = blockIdx.x * blockDim.x + threadIdx.x;
    if (t >= 169 * NH) return;
    int r = t / NH, h = t - (t / NH) * NH;
    int i = r / 13, j = r - (r / 13) * 13;
    float a0 = (float)(i - 6) * (8.0f / 6.0f);
    float a1 = (float)(j - 6) * (8.0f / 6.0f);
    float c0 = copysignf(log2f(fabsf(a0) + 1.0f) * (1.0f / 3.0f), a0);
    float c1 = copysignf(log2f(fabsf(a1) + 1.0f) * (1.0f / 3.0f), a1);
    float sum = 0.f;
    for (int k = 0; k < 512; ++k) {
        float hid = c0 * w1[2 * k] + c1 * w1[2 * k + 1] + b1[k];
        hid = fmaxf(hid, 0.f);
        sum += hid * w2[h * 512 + k];
    }
    bias_tab[r * NH + h] = sum;
}

// ---------------- rpbT[h][k][q] = 16*sigmoid(bias_tab[rpi(q,k)][h]) ----------------
__global__ void rpbT_kernel(const float* __restrict__ bias_tab, float* __restrict__ rpbT) {
    int idx = blockIdx.x * blockDim.x + threadIdx.x;
    if (idx >= NH * NTOK * NTOK) return;
    int h = idx / (NTOK * NTOK);
    int rem = idx - h * (NTOK * NTOK);
    int kj = rem / NTOK, qi = rem - (rem / NTOK) * NTOK;
    int chi = qi / 7, cwi = qi - chi * 7;
    int chj = kj / 7, cwj = kj - chj * 7;
    int rpi = (chi - chj + 6) * 13 + (cwi - cwj + 6);
    float x = bias_tab[rpi * NH + h];
    rpbT[idx] = 16.f / (1.f + __expf(-x));
}

// ---------------- maskT[w][k][q] = mask[w][q][k] ----------------
__global__ void maskT_kernel(const float* __restrict__ mask, float* __restrict__ maskT) {
    int idx = blockIdx.x * blockDim.x + threadIdx.x;
    if (idx >= NWIN * NTOK * NTOK) return;
    int w = idx / (NTOK * NTOK);
    int rem = idx - w * (NTOK * NTOK);
    int kj = rem / NTOK, qi = rem - (rem / NTOK) * NTOK;
    maskT[idx] = mask[(w * NTOK + qi) * NTOK + kj];
}

// ---------------- fused window-attention: one window per block, 4 waves ----------------
// LDS map (161792 B):
//   XW  @0      : x-window [64][384] bf16, 16B slots XOR-swizzled (49152 B)
//   AT  @49152  : 4 x 15872 per-wave attn scratch (Kl/Ql/Vl pad-40, invq, invk; P overlays)
//   AO  @112640 : attn-out [64][384] bf16, swizzled (49152 B)
// Phase 1 per wave: for 3 heads: qkv 64x96x384 MFMA (A from XW-LDS, B direct-from-L2,
// 3-deep reg prefetch) -> scratch -> attn2 core (verbatim) -> O into AO columns.
// Phase 2: 4-wave proj 64x384x384 from AO -> f32 out (+bias).
#define SWZ(row, byteInRow) ((row) * 768 + ((byteInRow) ^ (((row) & 7) << 4)))

__global__ __launch_bounds__(256, 1) void fused_win(
    const float* __restrict__ x, const __bf16* __restrict__ Wqkv,
    const __bf16* __restrict__ Wproj,
    const float* __restrict__ qbias, const float* __restrict__ vbias,
    const float* __restrict__ maskT, const float* __restrict__ rpbT,
    const float* __restrict__ lscale, const float* __restrict__ projb,
    float* __restrict__ out)
{
    __shared__ char smem[161792];
    char* XW = smem;
    char* AT = smem + 49152;
    char* AO = smem + 112640;

    const int tid = threadIdx.x;
    const int wid = tid >> 6, lane = tid & 63;
    const int c = lane & 15, g = lane >> 4;
    const int blk = blockIdx.x;
    const int w = blk & (NWIN - 1);

    // ---- phase 0: stage x window (f32 -> bf16, swizzled) ----
#pragma unroll
    for (int i = 0; i < 12; ++i) {
        const int s = i * 256 + tid;             // 3072 chunks of 8 elems
        const int row = s / 48, cp = s - (s / 48) * 48;
        bf16x8 v;
        if (row < NTOK) {
            const float* p = x + ((size_t)blk * NTOK + row) * CDIM + cp * 8;
            f32x4 a = *(const f32x4*)p;
            f32x4 b = *(const f32x4*)(p + 4);
#pragma unroll
            for (int e = 0; e < 4; ++e) { v[e] = (__bf16)a[e]; v[e + 4] = (__bf16)b[e]; }
        } else {
#pragma unroll
            for (int e = 0; e < 8; ++e) v[e] = (__bf16)0.f;
        }
        *(bf16x8*)(XW + SWZ(row, cp * 16)) = v;
    }
    __syncthreads();

    char* base = AT + wid * 15872;
    __bf16* Kl = (__bf16*)base;
    __bf16* Ql = (__bf16*)(base + 5120);
    __bf16* Vl = (__bf16*)(base + 10240);
    float* invq = (float*)(base + 15360);
    float* invk = (float*)(base + 15616);
    char* Pl = base;

    // ---- phase 1: each wave owns heads {wid, 4+wid, 8+wid} ----
    for (int hi = 0; hi < 3; ++hi) {
        const int h = hi * 4 + wid;
        const float sc = __expf(fminf(lscale[h], 4.6051702f));

        // qkv GEMM: out 64 x 96 (cols: q 0-31, k 32-63, v 64-95), K=384
        f32x4 acc[4][6];
#pragma unroll
        for (int m = 0; m < 4; ++m)
#pragma unroll
            for (int n = 0; n < 6; ++n) acc[m][n] = (f32x4){0.f, 0.f, 0.f, 0.f};

        size_t boff[6];
#pragma unroll
        for (int n = 0; n < 6; ++n)
            boff[n] = (size_t)((n >> 1) * CDIM + 32 * h + (n & 1) * 16 + c) * CDIM + g * 8;

#define QLD(arr, t) do {                                              \
        arr[0] = *(const bf16x8*)(Wqkv + boff[0] + (t) * 32);         \
        arr[1] = *(const bf16x8*)(Wqkv + boff[1] + (t) * 32);         \
        arr[2] = *(const bf16x8*)(Wqkv + boff[2] + (t) * 32);         \
        arr[3] = *(const bf16x8*)(Wqkv + boff[3] + (t) * 32);         \
        arr[4] = *(const bf16x8*)(Wqkv + boff[4] + (t) * 32);         \
        arr[5] = *(const bf16x8*)(Wqkv + boff[5] + (t) * 32);         \
    } while (0)

        bf16x8 b0[6], b1[6], b2[6];
        QLD(b0, 0); QLD(b1, 1); QLD(b2, 2);

#pragma unroll
        for (int t = 0; t < 12; ++t) {
            bf16x8 af[4];
#pragma unroll
            for (int m = 0; m < 4; ++m)
                af[m] = *(const bf16x8*)(XW + SWZ(m * 16 + c, t * 64 + g * 16));
            if (t % 3 == 0) {
#pragma unroll
                for (int m = 0; m < 4; ++m)
#pragma unroll
                    for (int n = 0; n < 6; ++n)
                        acc[m][n] = __builtin_amdgcn_mfma_f32_16x16x32_bf16(af[m], b0[n], acc[m][n], 0, 0, 0);
                if (t + 3 < 12) QLD(b0, t + 3);
            } else if (t % 3 == 1) {
#pragma unroll
                for (int m = 0; m < 4; ++m)
#pragma unroll
                    for (int n = 0; n < 6; ++n)
                        acc[m][n] = __builtin_amdgcn_mfma_f32_16x16x32_bf16(af[m], b1[n], acc[m][n], 0, 0, 0);
                if (t + 3 < 12) QLD(b1, t + 3);
            } else {
#pragma unroll
                for (int m = 0; m < 4; ++m)
#pragma unroll
                    for (int n = 0; n < 6; ++n)
                        acc[m][n] = __builtin_amdgcn_mfma_f32_16x16x32_bf16(af[m], b2[n], acc[m][n], 0, 0, 0);
                if (t + 3 < 12) QLD(b2, t + 3);
            }
        }
#undef QLD

        // bias + store q/k/v to per-wave pad-40 scratch
        float qb_[2], vb_[2];
#pragma unroll
        for (int n2 = 0; n2 < 2; ++n2) {
            qb_[n2] = qbias[32 * h + n2 * 16 + c];
            vb_[n2] = vbias[32 * h + n2 * 16 + c];
        }
#pragma unroll
        for (int m = 0; m < 4; ++m)
#pragma unroll
            for (int n = 0; n < 6; ++n) {
                __bf16* dst = (n < 2) ? Ql : (n < 4 ? Kl : Vl);
                const float bias = (n < 2) ? qb_[n & 1] : (n >= 4 ? vb_[n & 1] : 0.f);
                const int col = (n & 1) * 16 + c;
#pragma unroll
                for (int r = 0; r < 4; ++r) {
                    const int row = m * 16 + g * 4 + r;
                    dst[row * 40 + col] = (__bf16)(acc[m][n][r] + bias);
                }
            }

        // norms (lane = row, reads bf16-rounded values — matches attn2 numerics)
        {
            const int row = lane;
            float ss = 0.f;
#pragma unroll
            for (int ch = 0; ch < 4; ++ch) {
                bf16x8 tq = *(const bf16x8*)&Ql[row * 40 + ch * 8];
#pragma unroll
                for (int e = 0; e < 8; ++e) { float f = (float)tq[e]; ss += f * f; }
            }
            invq[row] = sc / fmaxf(sqrtf(ss), 1e-12f);
            ss = 0.f;
#pragma unroll
            for (int ch = 0; ch < 4; ++ch) {
                bf16x8 tk = *(const bf16x8*)&Kl[row * 40 + ch * 8];
#pragma unroll
                for (int e = 0; e < 8; ++e) { float f = (float)tk[e]; ss += f * f; }
            }
            invk[row] = 1.f / fmaxf(sqrtf(ss), 1e-12f);
        }

        // ---- attn2 core (verbatim) ----
        bf16x8 kfr[4], qfr[4];
#pragma unroll
        for (int mt = 0; mt < 4; ++mt) kfr[mt] = *(const bf16x8*)&Kl[(mt * 16 + c) * 40 + g * 8];
#pragma unroll
        for (int nt = 0; nt < 4; ++nt) qfr[nt] = *(const bf16x8*)&Ql[(nt * 16 + c) * 40 + g * 8];
        f32x4 S[4][4];
#pragma unroll
        for (int mt = 0; mt < 4; ++mt)
#pragma unroll
            for (int nt = 0; nt < 4; ++nt) {
                S[mt][nt] = (f32x4){0.f, 0.f, 0.f, 0.f};
                S[mt][nt] = __builtin_amdgcn_mfma_f32_16x16x32_bf16(kfr[mt], qfr[nt], S[mt][nt], 0, 0, 0);
            }

        const float* rp = rpbT + h * (NTOK * NTOK);
        const float* mk = maskT + w * (NTOK * NTOK);
        float ivq[4];
#pragma unroll
        for (int nt = 0; nt < 4; ++nt) ivq[nt] = invq[nt * 16 + c];
#pragma unroll
        for (int mt = 0; mt < 4; ++mt) {
#pragma unroll
            for (int r = 0; r < 4; ++r) {
                const int k = mt * 16 + g * 4 + r;
                const float ivk = invk[k];
#pragma unroll
                for (int nt = 0; nt < 4; ++nt) {
                    const int q = nt * 16 + c;
                    float v = S[mt][nt][r] * ivk * ivq[nt];
                    if (k < NTOK) {
                        if (q < NTOK) v += rp[k * NTOK + q] + mk[k * NTOK + q];
                    } else {
                        v = -1e30f;
                    }
                    S[mt][nt][r] = v;
                }
            }
        }

        float rs[4];
#pragma unroll
        for (int nt = 0; nt < 4; ++nt) {
            float m = -1e30f;
#pragma unroll
            for (int mt = 0; mt < 4; ++mt)
#pragma unroll
                for (int r = 0; r < 4; ++r) m = fmaxf(m, S[mt][nt][r]);
            m = fmaxf(m, __shfl_xor(m, 16));
            m = fmaxf(m, __shfl_xor(m, 32));
            float s = 0.f;
#pragma unroll
            for (int mt = 0; mt < 4; ++mt)
#pragma unroll
                for (int r = 0; r < 4; ++r) {
                    float e = __expf(S[mt][nt][r] - m);
                    S[mt][nt][r] = e;
                    s += e;
                }
            s += __shfl_xor(s, 16);
            s += __shfl_xor(s, 32);
            rs[nt] = 1.f / s;
        }

#pragma unroll
        for (int mt = 0; mt < 4; ++mt)
#pragma unroll
            for (int nt = 0; nt < 4; ++nt) {
                bf16x4 pk;
#pragma unroll
                for (int r = 0; r < 4; ++r) pk[r] = (__bf16)(S[mt][nt][r] * rs[nt]);
                *(bf16x4*)(Pl + (nt * 16 + c) * 144 + (mt * 16 + g * 4) * 2) = pk;
            }

        bf16x8 vfr[2][2];
#pragma unroll
        for (int kt = 0; kt < 2; ++kt)
#pragma unroll
            for (int dt = 0; dt < 2; ++dt) {
                bf16x8 t;
#pragma unroll
                for (int e = 0; e < 8; ++e) t[e] = Vl[(kt * 32 + g * 8 + e) * 40 + dt * 16 + c];
                vfr[kt][dt] = t;
            }
        f32x4 O[4][2];
#pragma unroll
        for (int mt = 0; mt < 4; ++mt)
#pragma unroll
            for (int dt = 0; dt < 2; ++dt) O[mt][dt] = (f32x4){0.f, 0.f, 0.f, 0.f};
#pragma unroll
        for (int mt = 0; mt < 4; ++mt)
#pragma unroll
            for (int kt = 0; kt < 2; ++kt) {
                bf16x8 pfr = *(const bf16x8*)(Pl + (mt * 16 + c) * 144 + kt * 64 + g * 16);
#pragma unroll
                for (int dt = 0; dt < 2; ++dt)
                    O[mt][dt] = __builtin_amdgcn_mfma_f32_16x16x32_bf16(pfr, vfr[kt][dt], O[mt][dt], 0, 0, 0);
            }

        // O -> AO columns [32h, 32h+32) (all 64 rows; pad rows harmless, row-local in proj)
#pragma unroll
        for (int mt = 0; mt < 4; ++mt)
#pragma unroll
            for (int r = 0; r < 4; ++r) {
                const int q = mt * 16 + g * 4 + r;
                *(__bf16*)(AO + SWZ(q, (32 * h + c) * 2)) = (__bf16)O[mt][0][r];
                *(__bf16*)(AO + SWZ(q, (32 * h + 16 + c) * 2)) = (__bf16)O[mt][1][r];
            }
    }

    __syncthreads();

    // ---- phase 2: proj 64x384x384, wave cols [wid*96, wid*96+96) ----
    {
        f32x4 acc[4][6];
#pragma unroll
        for (int m = 0; m < 4; ++m)
#pragma unroll
            for (int n = 0; n < 6; ++n) acc[m][n] = (f32x4){0.f, 0.f, 0.f, 0.f};

        size_t boff[6];
#pragma unroll
        for (int n = 0; n < 6; ++n)
            boff[n] = (size_t)(wid * 96 + n * 16 + c) * CDIM + g * 8;

#define PLD(arr, t) do {                                               \
        arr[0] = *(const bf16x8*)(Wproj + boff[0] + (t) * 32);         \
        arr[1] = *(const bf16x8*)(Wproj + boff[1] + (t) * 32);         \
        arr[2] = *(const bf16x8*)(Wproj + boff[2] + (t) * 32);         \
        arr[3] = *(const bf16x8*)(Wproj + boff[3] + (t) * 32);         \
        arr[4] = *(const bf16x8*)(Wproj + boff[4] + (t) * 32);         \
        arr[5] = *(const bf16x8*)(Wproj + boff[5] + (t) * 32);         \
    } while (0)

        bf16x8 b0[6], b1[6], b2[6];
        PLD(b0, 0); PLD(b1, 1); PLD(b2, 2);

#pragma unroll
        for (int t = 0; t < 12; ++t) {
            bf16x8 af[4];
#pragma unroll
            for (int m = 0; m < 4; ++m)
                af[m] = *(const bf16x8*)(AO + SWZ(m * 16 + c, t * 64 + g * 16));
            if (t % 3 == 0) {
#pragma unroll
                for (int m = 0; m < 4; ++m)
#pragma unroll
                    for (int n = 0; n < 6; ++n)
                        acc[m][n] = __builtin_amdgcn_mfma_f32_16x16x32_bf16(af[m], b0[n], acc[m][n], 0, 0, 0);
                if (t + 3 < 12) PLD(b0, t + 3);
            } else if (t % 3 == 1) {
#pragma unroll
                for (int m = 0; m < 4; ++m)
#pragma unroll
                    for (int n = 0; n < 6; ++n)
                        acc[m][n] = __builtin_amdgcn_mfma_f32_16x16x32_bf16(af[m], b1[n], acc[m][n], 0, 0, 0);
                if (t + 3 < 12) PLD(b1, t + 3);
            } else {
#pragma unroll
                for (int m = 0; m < 4; ++m)
#pragma unroll
                    for (int n = 0; n < 6; ++n)
                        acc[m][n] = __builtin_amdgcn_mfma_f32_16x16x32_bf16(af[m], b2[n], acc[m][n], 0, 0, 0);
                if (t + 3 < 12) PLD(b2, t + 3);
            }
        }
#undef PLD

        float pb[6];
#pragma unroll
        for (int n = 0; n < 6; ++n) pb[n] = projb[wid * 96 + n * 16 + c];
#pragma unroll
        for (int m = 0; m < 4; ++m)
#pragma unroll
            for (int r = 0; r < 4; ++r) {
                const int trow = m * 16 + g * 4 + r;
                if (trow < NTOK) {
                    float* orow = out + ((size_t)blk * NTOK + trow) * CDIM + wid * 96;
#pragma unroll
                    for (int n = 0; n < 6; ++n) orow[n * 16 + c] = acc[m][n][r] + pb[n];
                }
            }
    }
}

extern "C" void kernel_launch(void* const* d_in, const int* in_sizes, int n_in,
                              void* d_out, int out_size, void* d_ws, size_t ws_size,
                              hipStream_t stream) {
    const float* x      = (const float*)d_in[0];
    const float* mask   = (const float*)d_in[1];
    const float* qkv_w  = (const float*)d_in[2];
    const float* q_bias = (const float*)d_in[3];
    const float* v_bias = (const float*)d_in[4];
    const float* lscale = (const float*)d_in[5];
    const float* cpb_w1 = (const float*)d_in[6];
    const float* cpb_b1 = (const float*)d_in[7];
    const float* cpb_w2 = (const float*)d_in[8];
    const float* proj_w = (const float*)d_in[9];
    const float* proj_b = (const float*)d_in[10];
    float* out = (float*)d_out;

    __bf16* qkv_wb  = (__bf16*)d_ws;                    // 1152*384 bf16
    __bf16* proj_wb = qkv_wb + 1152 * CDIM;             // 384*384 bf16
    float*  bias_tab = (float*)(proj_wb + CDIM * CDIM); // 169*12
    float*  rpbT   = bias_tab + 169 * NH;               // 12*49*49
    float*  maskT  = rpbT + NH * NTOK * NTOK;           // 64*49*49

    hipLaunchKernelGGL(cvt_f32_bf16, dim3((1152 * CDIM / 8 + 255) / 256), dim3(256), 0, stream,
                       qkv_w, qkv_wb, 1152 * CDIM / 8);
    hipLaunchKernelGGL(cvt_f32_bf16, dim3((CDIM * CDIM / 8 + 255) / 256), dim3(256), 0, stream,
                       proj_w, proj_wb, CDIM * CDIM / 8);
    hipLaunchKernelGGL(cpb_mlp_kernel, dim3(8), dim3(256), 0, stream,
                       cpb_w1, cpb_b1, cpb_w2, bias_tab);
    hipLaunchKernelGGL(rpbT_kernel, dim3((NH * NTOK * NTOK + 255) / 256), dim3(256), 0, stream,
                       bias_tab, rpbT);
    hipLaunchKernelGGL(maskT_kernel, dim3((NWIN * NTOK * NTOK + 255) / 256), dim3(256), 0, stream,
                       mask, maskT);
    hipLaunchKernelGGL(fused_win, dim3(BWIN), dim3(256), 0, stream,
                       x, qkv_wb, proj_wb, q_bias, v_bias, maskT, rpbT, lscale, proj_b, out);
}

// Round 8
// 526.500 us; speedup vs baseline: 1.0538x; 1.0538x over previous
//
#include <hip/hip_runtime.h>
#include <hip/hip_bf16.h>
#include <math.h>

#define NTOK 49
#define NH 12
#define HD 32
#define CDIM 384
#define NWIN 64
#define BWIN 2048

typedef __bf16 bf16x8 __attribute__((ext_vector_type(8)));
typedef __bf16 bf16x4 __attribute__((ext_vector_type(4)));
typedef float f32x4 __attribute__((ext_vector_type(4)));

__device__ __forceinline__ void gload_lds16(const void* g, void* l) {
    __builtin_amdgcn_global_load_lds((const __attribute__((address_space(1))) void*)g,
                                     (__attribute__((address_space(3))) void*)l, 16, 0, 0);
}

// ---------------- fp32 -> bf16 convert (weights only) ----------------
__global__ void cvt_f32_bf16(const float* __restrict__ src, __bf16* __restrict__ dst, int n8) {
    int i = blockIdx.x * blockDim.x + threadIdx.x;
    if (i >= n8) return;
    f32x4 a = *(const f32x4*)(src + (size_t)i * 8);
    f32x4 b = *(const f32x4*)(src + (size_t)i * 8 + 4);
    bf16x8 o;
#pragma unroll
    for (int e = 0; e < 4; ++e) { o[e] = (__bf16)a[e]; o[e + 4] = (__bf16)b[e]; }
    *(bf16x8*)(dst + (size_t)i * 8) = o;
}

// ---------------- CPB MLP: bias_tab[169][12] ----------------
__global__ void cpb_mlp_kernel(const float* __restrict__ w1, const float* __restrict__ b1,
                               const float* __restrict__ w2, float* __restrict__ bias_tab) {
    int t = blockIdx.x * blockDim.x + threadIdx.x;
    if (t >= 169 * NH) return;
    int r = t / NH, h = t - (t / NH) * NH;
    int i = r / 13, j = r - (r / 13) * 13;
    float a0 = (float)(i - 6) * (8.0f / 6.0f);
    float a1 = (float)(j - 6) * (8.0f / 6.0f);
    float c0 = copysignf(log2f(fabsf(a0) + 1.0f) * (1.0f / 3.0f), a0);
    float c1 = copysignf(log2f(fabsf(a1) + 1.0f) * (1.0f / 3.0f), a1);
    float sum = 0.f;
    for (int k = 0; k < 512; ++k) {
        float hid = c0 * w1[2 * k] + c1 * w1[2 * k + 1] + b1[k];
        hid = fmaxf(hid, 0.f);
        sum += hid * w2[h * 512 + k];
    }
    bias_tab[r * NH + h] = sum;
}

// ---------------- rpbT[h][k][q] = 16*sigmoid(bias_tab[rpi(q,k)][h]) ----------------
__global__ void rpbT_kernel(const float* __restrict__ bias_tab, float* __restrict__ rpbT) {
    int idx = blockIdx.x * blockDim.x + threadIdx.x;
    if (idx >= NH * NTOK * NTOK) return;
    int h = idx / (NTOK * NTOK);
    int rem = idx - h * (NTOK * NTOK);
    int kj = rem / NTOK, qi = rem - (rem / NTOK) * NTOK;
    int chi = qi / 7, cwi = qi - chi * 7;
    int chj = kj / 7, cwj = kj - chj * 7;
    int rpi = (chi - chj + 6) * 13 + (cwi - cwj + 6);
    float x = bias_tab[rpi * NH + h];
    rpbT[idx] = 16.f / (1.f + __expf(-x));
}

// ---------------- maskT[w][k][q] = mask[w][q][k] ----------------
__global__ void maskT_kernel(const float* __restrict__ mask, float* __restrict__ maskT) {
    int idx = blockIdx.x * blockDim.x + threadIdx.x;
    if (idx >= NWIN * NTOK * NTOK) return;
    int w = idx / (NTOK * NTOK);
    int rem = idx - w * (NTOK * NTOK);
    int kj = rem / NTOK, qi = rem - (rem / NTOK) * NTOK;
    maskT[idx] = mask[(w * NTOK + qi) * NTOK + kj];
}

// ---------------- qkv GEMM: f32 A reg-staged (fused convert), B gload_lds ----------------
// A tile [128][32] f32 -> bf16 via reg-staging: thread (row=tid>>1, half=tid&1) loads
// 16 f32 one iter ahead, converts, ds_writes to XOR-swizzled slots (write-side swizzle;
// read side identical to R5). B: 3-buffer gload_lds w/ source-pre-swizzle.
// vmcnt audit: per iter issue A(t+2)x4 then B(t+2)x2 => at iter top vmcnt(2) ensures
// A(t+1) regs + B(t) LDS landed with B(t+1),B(t+2)-issue pipelining preserved.
__global__ __launch_bounds__(256) void gemm_qkv(
    const float* __restrict__ X, const __bf16* __restrict__ Bw,
    const float* __restrict__ qbias, const float* __restrict__ vbias,
    __bf16* __restrict__ qkvout)
{
    __shared__ __bf16 As[3][128 * 32];
    __shared__ __bf16 Bs[3][128 * 32];
    const int tid = threadIdx.x;
    const int chunk = (784 * 9) >> 3;
    const int wg = (blockIdx.x & 7) * chunk + (blockIdx.x >> 3);
    const int gx = wg / 9, gy = wg - (wg / 9) * 9;
    const int lane = tid & 63;
    const int wid = tid >> 6;
    const int wr = (wid >> 1) * 64;
    const int wc = (wid & 1) * 64;
    const int fr = lane & 15;
    const int fq = lane >> 4;

    f32x4 acc[4][4];
#pragma unroll
    for (int m = 0; m < 4; ++m)
#pragma unroll
        for (int n = 0; n < 4; ++n)
            acc[m][n] = (f32x4){0.f, 0.f, 0.f, 0.f};

    // A staging geometry: 2 threads/row, 16 f32 each
    const int arow = tid >> 1, ahalf = tid & 1;
    const float* aptr = X + (size_t)(gx * 128 + arow) * CDIM + ahalf * 16;
    const int aswz = (arow >> 1) & 3;
    const int ap0 = (ahalf * 2) ^ aswz;      // phys 16B slot for logical chunk 2*ahalf
    const int ap1 = (ahalf * 2 + 1) ^ aswz;

    // B staging geometry (source-pre-swizzled gload_lds)
    const int srow0 = tid >> 2, scp0 = tid & 3;
    const int srow1 = (256 + tid) >> 2;
    const size_t br0 = (size_t)(gy * 128 + srow0) * CDIM + (scp0 ^ ((srow0 >> 1) & 3)) * 8;
    const size_t br1 = (size_t)(gy * 128 + srow1) * CDIM + (scp0 ^ ((srow1 >> 1) & 3)) * 8;
    const int ls0 = tid * 16, ls1 = (256 + tid) * 16;

    f32x4 av0, av1, av2, av3;
#define ALOAD(ti) do {                                \
        av0 = *(const f32x4*)(aptr + (ti) * 32);      \
        av1 = *(const f32x4*)(aptr + (ti) * 32 + 4);  \
        av2 = *(const f32x4*)(aptr + (ti) * 32 + 8);  \
        av3 = *(const f32x4*)(aptr + (ti) * 32 + 12); \
    } while (0)
#define AWRITE(buf) do {                                                 \
        bf16x8 c0, c1;                                                   \
        for (int e = 0; e < 4; ++e) {                                    \
            c0[e] = (__bf16)av0[e]; c0[e + 4] = (__bf16)av1[e];          \
            c1[e] = (__bf16)av2[e]; c1[e + 4] = (__bf16)av3[e];          \
        }                                                                \
        *(bf16x8*)&As[buf][arow * 32 + ap0 * 8] = c0;                    \
        *(bf16x8*)&As[buf][arow * 32 + ap1 * 8] = c1;                    \
    } while (0)
#define BSTAGE(ti, buf) do {                                             \
        const int kk_ = (ti) * 32;                                       \
        gload_lds16(Bw + br0 + kk_, (char*)&Bs[buf][0] + ls0);           \
        gload_lds16(Bw + br1 + kk_, (char*)&Bs[buf][0] + ls1);           \
    } while (0)

    // prologue: A(0) B(0) A(1) B(1) issued; A(0) landed -> write As[0]
    ALOAD(0);
    BSTAGE(0, 0);
    {
        f32x4 t0 = av0, t1 = av1, t2 = av2, t3 = av3;  // keep A(0) while issuing A(1)
        ALOAD(1);
        BSTAGE(1, 1);
        f32x4 s0 = av0, s1 = av1, s2 = av2, s3 = av3;
        av0 = t0; av1 = t1; av2 = t2; av3 = t3;
        asm volatile("s_waitcnt vmcnt(8)" ::: "memory");
        AWRITE(0);
        av0 = s0; av1 = s1; av2 = s2; av3 = s3;        // A(1) regs (compiler waits on use)
    }

#pragma unroll
    for (int t = 0; t < 12; ++t) {
        if (t < 11) asm volatile("s_waitcnt vmcnt(2)" ::: "memory");
        else        asm volatile("s_waitcnt vmcnt(0)" ::: "memory");
        asm volatile("s_waitcnt lgkmcnt(0)" ::: "memory");
        __builtin_amdgcn_s_barrier();
        if (t + 1 < 12) AWRITE((t + 1) % 3);   // regs hold A(t+1)
        if (t + 2 < 12) {
            ALOAD(t + 2);                       // overwrite regs with A(t+2)
            BSTAGE(t + 2, (t + 2) % 3);
        }
        const int cur = t % 3;
        bf16x8 af[4], bfr[4];
#pragma unroll
        for (int m = 0; m < 4; ++m) {
            const int row = wr + m * 16 + fr;
            af[m] = *(const bf16x8*)&As[cur][row * 32 + (fq ^ ((row >> 1) & 3)) * 8];
        }
#pragma unroll
        for (int n = 0; n < 4; ++n) {
            const int row = wc + n * 16 + fr;
            bfr[n] = *(const bf16x8*)&Bs[cur][row * 32 + (fq ^ ((row >> 1) & 3)) * 8];
        }
#pragma unroll
        for (int m = 0; m < 4; ++m)
#pragma unroll
            for (int n = 0; n < 4; ++n)
                acc[m][n] = __builtin_amdgcn_mfma_f32_16x16x32_bf16(af[m], bfr[n], acc[m][n], 0, 0, 0);
    }
#undef ALOAD
#undef AWRITE
#undef BSTAGE

    // epilogue: scatter to q/k/v [b][h][n][d] (+q/v bias)
    const int colbase = gy * 128;
    const int part = colbase / CDIM;
    const int pcolbase = colbase - part * CDIM;
    __bf16* dst = qkvout + (size_t)part * ((size_t)BWIN * NH * NTOK * HD);
#pragma unroll
    for (int m = 0; m < 4; ++m) {
#pragma unroll
        for (int r = 0; r < 4; ++r) {
            const int row = gx * 128 + wr + m * 16 + fq * 4 + r;
            const int b = row / NTOK;
            const int nn = row - b * NTOK;
#pragma unroll
            for (int n = 0; n < 4; ++n) {
                const int pcol = pcolbase + wc + n * 16 + fr;
                float val = acc[m][n][r];
                if (part == 0) val += qbias[pcol];
                if (part == 2) val += vbias[pcol];
                const int h = pcol >> 5, d = pcol & 31;
                dst[(((size_t)b * NH + h) * NTOK + nn) * HD + d] = (__bf16)val;
            }
        }
    }
}

// ---------------- proj GEMM: bf16 A+B via gload_lds, 3-buffer counted vmcnt (R5) ----------------
__global__ __launch_bounds__(256) void gemm_proj(
    const __bf16* __restrict__ A, const __bf16* __restrict__ Bw,
    float* __restrict__ fout, const float* __restrict__ fbias)
{
    __shared__ __bf16 As[3][128 * 32];
    __shared__ __bf16 Bs[3][128 * 32];
    const int tid = threadIdx.x;
    const int chunk = (784 * 3) >> 3;
    const int wg = (blockIdx.x & 7) * chunk + (blockIdx.x >> 3);
    const int gx = wg / 3, gy = wg - (wg / 3) * 3;
    const int lane = tid & 63;
    const int wid = tid >> 6;
    const int wr = (wid >> 1) * 64;
    const int wc = (wid & 1) * 64;
    const int fr = lane & 15;
    const int fq = lane >> 4;

    f32x4 acc[4][4];
#pragma unroll
    for (int m = 0; m < 4; ++m)
#pragma unroll
        for (int n = 0; n < 4; ++n)
            acc[m][n] = (f32x4){0.f, 0.f, 0.f, 0.f};

    const int srow0 = tid >> 2, scp0 = tid & 3;
    const int srow1 = (256 + tid) >> 2;
    const size_t ar0 = (size_t)(gx * 128 + srow0) * CDIM + (scp0 ^ ((srow0 >> 1) & 3)) * 8;
    const size_t ar1 = (size_t)(gx * 128 + srow1) * CDIM + (scp0 ^ ((srow1 >> 1) & 3)) * 8;
    const size_t br0 = (size_t)(gy * 128 + srow0) * CDIM + (scp0 ^ ((srow0 >> 1) & 3)) * 8;
    const size_t br1 = (size_t)(gy * 128 + srow1) * CDIM + (scp0 ^ ((srow1 >> 1) & 3)) * 8;
    const int ls0 = tid * 16, ls1 = (256 + tid) * 16;

#define STAGE(ti, buf) do {                                              \
        const int kk_ = (ti) * 32;                                       \
        gload_lds16(A + ar0 + kk_, (char*)&As[buf][0] + ls0);            \
        gload_lds16(A + ar1 + kk_, (char*)&As[buf][0] + ls1);            \
        gload_lds16(Bw + br0 + kk_, (char*)&Bs[buf][0] + ls0);           \
        gload_lds16(Bw + br1 + kk_, (char*)&Bs[buf][0] + ls1);           \
    } while (0)

    STAGE(0, 0);
    STAGE(1, 1);

#pragma unroll
    for (int t = 0; t < 12; ++t) {
        if (t < 11) asm volatile("s_waitcnt vmcnt(4)" ::: "memory");
        else        asm volatile("s_waitcnt vmcnt(0)" ::: "memory");
        __builtin_amdgcn_s_barrier();
        if (t + 2 < 12) STAGE(t + 2, (t + 2) % 3);
        const int cur = t % 3;
        bf16x8 af[4], bfr[4];
#pragma unroll
        for (int m = 0; m < 4; ++m) {
            const int row = wr + m * 16 + fr;
            af[m] = *(const bf16x8*)&As[cur][row * 32 + (fq ^ ((row >> 1) & 3)) * 8];
        }
#pragma unroll
        for (int n = 0; n < 4; ++n) {
            const int row = wc + n * 16 + fr;
            bfr[n] = *(const bf16x8*)&Bs[cur][row * 32 + (fq ^ ((row >> 1) & 3)) * 8];
        }
#pragma unroll
        for (int m = 0; m < 4; ++m)
#pragma unroll
            for (int n = 0; n < 4; ++n)
                acc[m][n] = __builtin_amdgcn_mfma_f32_16x16x32_bf16(af[m], bfr[n], acc[m][n], 0, 0, 0);
    }
#undef STAGE

#pragma unroll
    for (int m = 0; m < 4; ++m) {
#pragma unroll
        for (int r = 0; r < 4; ++r) {
            const int row = gx * 128 + wr + m * 16 + fq * 4 + r;
            float* orow = fout + (size_t)row * CDIM + gy * 128 + wc;
#pragma unroll
            for (int n = 0; n < 4; ++n) {
                const int col = gy * 128 + wc + n * 16 + fr;
                orow[n * 16 + fr] = acc[m][n][r] + fbias[col];
            }
        }
    }
}

// ---------------- attention: MFMA, one (b,h) per wave, 4 waves/block (R5 verbatim) ----------------
#define WREG 15872
__global__ __launch_bounds__(256) void attn2(
    const __bf16* __restrict__ qb, const __bf16* __restrict__ kb,
    const __bf16* __restrict__ vb, const float* __restrict__ maskT,
    const float* __restrict__ rpbT, const float* __restrict__ lscale,
    __bf16* __restrict__ aout)
{
    __shared__ char smem[4 * WREG];
    const int tid = threadIdx.x;
    const int wid = tid >> 6, lane = tid & 63;
    const int bh = blockIdx.x * 4 + wid;
    const int b = bh / NH, h = bh - b * NH;
    const int w = b & (NWIN - 1);
    const int c = lane & 15, g = lane >> 4;

    char* base = smem + wid * WREG;
    __bf16* Kl = (__bf16*)base;
    __bf16* Ql = (__bf16*)(base + 5120);
    __bf16* Vl = (__bf16*)(base + 10240);
    float* invq = (float*)(base + 15360);
    float* invk = (float*)(base + 15616);
    char* Pl = base;

    const float sc = __expf(fminf(lscale[h], 4.6051702f));

    {
        const int row = lane;
        const size_t rb = (size_t)bh * (NTOK * HD) + (size_t)row * HD;
        bf16x8 z;
#pragma unroll
        for (int e = 0; e < 8; ++e) z[e] = (__bf16)0.f;
        {
            bf16x8 t[4];
            float ss = 0.f;
            if (row < NTOK) {
#pragma unroll
                for (int ch = 0; ch < 4; ++ch) {
                    t[ch] = *(const bf16x8*)(qb + rb + ch * 8);
#pragma unroll
                    for (int e = 0; e < 8; ++e) { float f = (float)t[ch][e]; ss += f * f; }
                }
            } else {
#pragma unroll
                for (int ch = 0; ch < 4; ++ch) t[ch] = z;
            }
#pragma unroll
            for (int ch = 0; ch < 4; ++ch) *(bf16x8*)&Ql[row * 40 + ch * 8] = t[ch];
            invq[row] = sc / fmaxf(sqrtf(ss), 1e-12f);
        }
        {
            bf16x8 t[4];
            float ss = 0.f;
            if (row < NTOK) {
#pragma unroll
                for (int ch = 0; ch < 4; ++ch) {
                    t[ch] = *(const bf16x8*)(kb + rb + ch * 8);
#pragma unroll
                    for (int e = 0; e < 8; ++e) { float f = (float)t[ch][e]; ss += f * f; }
                }
            } else {
#pragma unroll
                for (int ch = 0; ch < 4; ++ch) t[ch] = z;
            }
#pragma unroll
            for (int ch = 0; ch < 4; ++ch) *(bf16x8*)&Kl[row * 40 + ch * 8] = t[ch];
            invk[row] = 1.f / fmaxf(sqrtf(ss), 1e-12f);
        }
        {
            bf16x8 t[4];
            if (row < NTOK) {
#pragma unroll
                for (int ch = 0; ch < 4; ++ch) t[ch] = *(const bf16x8*)(vb + rb + ch * 8);
            } else {
#pragma unroll
                for (int ch = 0; ch < 4; ++ch) t[ch] = z;
            }
#pragma unroll
            for (int ch = 0; ch < 4; ++ch) *(bf16x8*)&Vl[row * 40 + ch * 8] = t[ch];
        }
    }

    bf16x8 kfr[4], qfr[4];
#pragma unroll
    for (int mt = 0; mt < 4; ++mt) kfr[mt] = *(const bf16x8*)&Kl[(mt * 16 + c) * 40 + g * 8];
#pragma unroll
    for (int nt = 0; nt < 4; ++nt) qfr[nt] = *(const bf16x8*)&Ql[(nt * 16 + c) * 40 + g * 8];
    f32x4 S[4][4];
#pragma unroll
    for (int mt = 0; mt < 4; ++mt)
#pragma unroll
        for (int nt = 0; nt < 4; ++nt) {
            S[mt][nt] = (f32x4){0.f, 0.f, 0.f, 0.f};
            S[mt][nt] = __builtin_amdgcn_mfma_f32_16x16x32_bf16(kfr[mt], qfr[nt], S[mt][nt], 0, 0, 0);
        }

    const float* rp = rpbT + h * (NTOK * NTOK);
    const float* mk = maskT + w * (NTOK * NTOK);
    float ivq[4];
#pragma unroll
    for (int nt = 0; nt < 4; ++nt) ivq[nt] = invq[nt * 16 + c];
#pragma unroll
    for (int mt = 0; mt < 4; ++mt) {
#pragma unroll
        for (int r = 0; r < 4; ++r) {
            const int k = mt * 16 + g * 4 + r;
            const float ivk = invk[k];
#pragma unroll
            for (int nt = 0; nt < 4; ++nt) {
                const int q = nt * 16 + c;
                float v = S[mt][nt][r] * ivk * ivq[nt];
                if (k < NTOK) {
                    if (q < NTOK) v += rp[k * NTOK + q] + mk[k * NTOK + q];
                } else {
                    v = -1e30f;
                }
                S[mt][nt][r] = v;
            }
        }
    }

    float rs[4];
#pragma unroll
    for (int nt = 0; nt < 4; ++nt) {
        float m = -1e30f;
#pragma unroll
        for (int mt = 0; mt < 4; ++mt)
#pragma unroll
            for (int r = 0; r < 4; ++r) m = fmaxf(m, S[mt][nt][r]);
        m = fmaxf(m, __shfl_xor(m, 16));
        m = fmaxf(m, __shfl_xor(m, 32));
        float s = 0.f;
#pragma unroll
        for (int mt = 0; mt < 4; ++mt)
#pragma unroll
            for (int r = 0; r < 4; ++r) {
                float e = __expf(S[mt][nt][r] - m);
                S[mt][nt][r] = e;
                s += e;
            }
        s += __shfl_xor(s, 16);
        s += __shfl_xor(s, 32);
        rs[nt] = 1.f / s;
    }

#pragma unroll
    for (int mt = 0; mt < 4; ++mt)
#pragma unroll
        for (int nt = 0; nt < 4; ++nt) {
            bf16x4 pk;
#pragma unroll
            for (int r = 0; r < 4; ++r) pk[r] = (__bf16)(S[mt][nt][r] * rs[nt]);
            *(bf16x4*)(Pl + (nt * 16 + c) * 144 + (mt * 16 + g * 4) * 2) = pk;
        }

    bf16x8 vfr[2][2];
#pragma unroll
    for (int kt = 0; kt < 2; ++kt)
#pragma unroll
        for (int dt = 0; dt < 2; ++dt) {
            bf16x8 t;
#pragma unroll
            for (int e = 0; e < 8; ++e) t[e] = Vl[(kt * 32 + g * 8 + e) * 40 + dt * 16 + c];
            vfr[kt][dt] = t;
        }
    f32x4 O[4][2];
#pragma unroll
    for (int mt = 0; mt < 4; ++mt)
#pragma unroll
        for (int dt = 0; dt < 2; ++dt) O[mt][dt] = (f32x4){0.f, 0.f, 0.f, 0.f};
#pragma unroll
    for (int mt = 0; mt < 4; ++mt)
#pragma unroll
        for (int kt = 0; kt < 2; ++kt) {
            bf16x8 pfr = *(const bf16x8*)(Pl + (mt * 16 + c) * 144 + kt * 64 + g * 16);
#pragma unroll
            for (int dt = 0; dt < 2; ++dt)
                O[mt][dt] = __builtin_amdgcn_mfma_f32_16x16x32_bf16(pfr, vfr[kt][dt], O[mt][dt], 0, 0, 0);
        }

#pragma unroll
    for (int mt = 0; mt < 4; ++mt)
#pragma unroll
        for (int r = 0; r < 4; ++r) {
            const int q = mt * 16 + g * 4 + r;
            if (q < NTOK) {
                const size_t off = ((size_t)b * NTOK + q) * CDIM + h * HD;
                aout[off + c] = (__bf16)O[mt][0][r];
                aout[off + 16 + c] = (__bf16)O[mt][1][r];
            }
        }
}

extern "C" void kernel_launch(void* const* d_in, const int* in_sizes, int n_in,
                              void* d_out, int out_size, void* d_ws, size_t ws_size,
                              hipStream_t stream) {
    const float* x      = (const float*)d_in[0];
    const float* mask   = (const float*)d_in[1];
    const float* qkv_w  = (const float*)d_in[2];
    const float* q_bias = (const float*)d_in[3];
    const float* v_bias = (const float*)d_in[4];
    const float* lscale = (const float*)d_in[5];
    const float* cpb_w1 = (const float*)d_in[6];
    const float* cpb_b1 = (const float*)d_in[7];
    const float* cpb_w2 = (const float*)d_in[8];
    const float* proj_w = (const float*)d_in[9];
    const float* proj_b = (const float*)d_in[10];
    float* out = (float*)d_out;

    const size_t QKVELEMS = (size_t)BWIN * NH * NTOK * HD;  // 100352*384
    __bf16* qkvbuf  = (__bf16*)d_ws;                    // q,k,v
    __bf16* aoutbuf = qkvbuf + 3 * QKVELEMS;            // attn out
    __bf16* qkv_wb  = aoutbuf + QKVELEMS;               // 1152*384 bf16
    __bf16* proj_wb = qkv_wb + 1152 * CDIM;             // 384*384 bf16
    float*  bias_tab = (float*)(proj_wb + CDIM * CDIM); // 169*12
    float*  rpbT   = bias_tab + 169 * NH;               // 12*49*49
    float*  maskT  = rpbT + NH * NTOK * NTOK;           // 64*49*49

    hipLaunchKernelGGL(cvt_f32_bf16, dim3((1152 * CDIM / 8 + 255) / 256), dim3(256), 0, stream,
                       qkv_w, qkv_wb, 1152 * CDIM / 8);
    hipLaunchKernelGGL(cvt_f32_bf16, dim3((CDIM * CDIM / 8 + 255) / 256), dim3(256), 0, stream,
                       proj_w, proj_wb, CDIM * CDIM / 8);
    hipLaunchKernelGGL(cpb_mlp_kernel, dim3(8), dim3(256), 0, stream,
                       cpb_w1, cpb_b1, cpb_w2, bias_tab);
    hipLaunchKernelGGL(rpbT_kernel, dim3((NH * NTOK * NTOK + 255) / 256), dim3(256), 0, stream,
                       bias_tab, rpbT);
    hipLaunchKernelGGL(maskT_kernel, dim3((NWIN * NTOK * NTOK + 255) / 256), dim3(256), 0, stream,
                       mask, maskT);
    hipLaunchKernelGGL(gemm_qkv, dim3(784 * 9), dim3(256), 0, stream,
                       x, qkv_wb, q_bias, v_bias, qkvbuf);
    hipLaunchKernelGGL(attn2, dim3(BWIN * NH / 4), dim3(256), 0, stream,
                       qkvbuf, qkvbuf + QKVELEMS, qkvbuf + 2 * QKVELEMS, maskT, rpbT, lscale,
                       aoutbuf);
    hipLaunchKernelGGL(gemm_proj, dim3(784 * 3), dim3(256), 0, stream,
                       aoutbuf, proj_wb, out, proj_b);
}

// Round 9
// 451.823 us; speedup vs baseline: 1.2279x; 1.1653x over previous
//
#include <hip/hip_runtime.h>
#include <hip/hip_bf16.h>
#include <math.h>

#define NTOK 49
#define NH 12
#define HD 32
#define CDIM 384
#define NWIN 64
#define BWIN 2048
#define QKVROW 1152

typedef __bf16 bf16x8 __attribute__((ext_vector_type(8)));
typedef __bf16 bf16x4 __attribute__((ext_vector_type(4)));
typedef float f32x4 __attribute__((ext_vector_type(4)));

__device__ __forceinline__ void gload_lds16(const void* g, void* l) {
    __builtin_amdgcn_global_load_lds((const __attribute__((address_space(1))) void*)g,
                                     (__attribute__((address_space(3))) void*)l, 16, 0, 0);
}

// ---------------- fp32 -> bf16 convert ----------------
__global__ void cvt_f32_bf16(const float* __restrict__ src, __bf16* __restrict__ dst, int n8) {
    int i = blockIdx.x * blockDim.x + threadIdx.x;
    if (i >= n8) return;
    f32x4 a = *(const f32x4*)(src + (size_t)i * 8);
    f32x4 b = *(const f32x4*)(src + (size_t)i * 8 + 4);
    bf16x8 o;
#pragma unroll
    for (int e = 0; e < 4; ++e) { o[e] = (__bf16)a[e]; o[e + 4] = (__bf16)b[e]; }
    *(bf16x8*)(dst + (size_t)i * 8) = o;
}

// ---------------- CPB MLP: bias_tab[169][12] ----------------
__global__ void cpb_mlp_kernel(const float* __restrict__ w1, const float* __restrict__ b1,
                               const float* __restrict__ w2, float* __restrict__ bias_tab) {
    int t = blockIdx.x * blockDim.x + threadIdx.x;
    if (t >= 169 * NH) return;
    int r = t / NH, h = t - (t / NH) * NH;
    int i = r / 13, j = r - (r / 13) * 13;
    float a0 = (float)(i - 6) * (8.0f / 6.0f);
    float a1 = (float)(j - 6) * (8.0f / 6.0f);
    float c0 = copysignf(log2f(fabsf(a0) + 1.0f) * (1.0f / 3.0f), a0);
    float c1 = copysignf(log2f(fabsf(a1) + 1.0f) * (1.0f / 3.0f), a1);
    float sum = 0.f;
    for (int k = 0; k < 512; ++k) {
        float hid = c0 * w1[2 * k] + c1 * w1[2 * k + 1] + b1[k];
        hid = fmaxf(hid, 0.f);
        sum += hid * w2[h * 512 + k];
    }
    bias_tab[r * NH + h] = sum;
}

// ---------------- rpbT[h][k][q] = 16*sigmoid(bias_tab[rpi(q,k)][h]) ----------------
__global__ void rpbT_kernel(const float* __restrict__ bias_tab, float* __restrict__ rpbT) {
    int idx = blockIdx.x * blockDim.x + threadIdx.x;
    if (idx >= NH * NTOK * NTOK) return;
    int h = idx / (NTOK * NTOK);
    int rem = idx - h * (NTOK * NTOK);
    int kj = rem / NTOK, qi = rem - (rem / NTOK) * NTOK;
    int chi = qi / 7, cwi = qi - chi * 7;
    int chj = kj / 7, cwj = kj - chj * 7;
    int rpi = (chi - chj + 6) * 13 + (cwi - cwj + 6);
    float x = bias_tab[rpi * NH + h];
    rpbT[idx] = 16.f / (1.f + __expf(-x));
}

// ---------------- maskT[w][k][q] = mask[w][q][k] ----------------
__global__ void maskT_kernel(const float* __restrict__ mask, float* __restrict__ maskT) {
    int idx = blockIdx.x * blockDim.x + threadIdx.x;
    if (idx >= NWIN * NTOK * NTOK) return;
    int w = idx / (NTOK * NTOK);
    int rem = idx - w * (NTOK * NTOK);
    int kj = rem / NTOK, qi = rem - (rem / NTOK) * NTOK;
    maskT[idx] = mask[(w * NTOK + qi) * NTOK + kj];
}

// ---------------- MFMA GEMM (R5 structure): 3-buffer counted-vmcnt, all-bf16 ----------------
// MODE 0: out -> qkv bf16 FLAT [row][1152] (+q/v bias) — coalesced writes (R8 theory).
// MODE 1: out -> f32 [row][384] (+proj bias).
template <int MODE, int NBY>
__global__ __launch_bounds__(256) void gemm6(
    const __bf16* __restrict__ A, const __bf16* __restrict__ Bw,
    const float* __restrict__ qbias, const float* __restrict__ vbias,
    __bf16* __restrict__ qkvout,
    float* __restrict__ fout, const float* __restrict__ fbias)
{
    __shared__ __bf16 As[3][128 * 32];
    __shared__ __bf16 Bs[3][128 * 32];
    const int tid = threadIdx.x;
    const int chunk = (784 * NBY) >> 3;
    const int wg = (blockIdx.x & 7) * chunk + (blockIdx.x >> 3);
    const int gx = wg / NBY, gy = wg - (wg / NBY) * NBY;
    const int lane = tid & 63;
    const int wid = tid >> 6;
    const int wr = (wid >> 1) * 64;
    const int wc = (wid & 1) * 64;
    const int fr = lane & 15;
    const int fq = lane >> 4;

    f32x4 acc[4][4];
#pragma unroll
    for (int m = 0; m < 4; ++m)
#pragma unroll
        for (int n = 0; n < 4; ++n)
            acc[m][n] = (f32x4){0.f, 0.f, 0.f, 0.f};

    const int srow0 = tid >> 2, scp0 = tid & 3;
    const int srow1 = (256 + tid) >> 2;
    const size_t ar0 = (size_t)(gx * 128 + srow0) * CDIM + (scp0 ^ ((srow0 >> 1) & 3)) * 8;
    const size_t ar1 = (size_t)(gx * 128 + srow1) * CDIM + (scp0 ^ ((srow1 >> 1) & 3)) * 8;
    const size_t br0 = (size_t)(gy * 128 + srow0) * CDIM + (scp0 ^ ((srow0 >> 1) & 3)) * 8;
    const size_t br1 = (size_t)(gy * 128 + srow1) * CDIM + (scp0 ^ ((srow1 >> 1) & 3)) * 8;
    const int ls0 = tid * 16, ls1 = (256 + tid) * 16;

#define STAGE(ti, buf) do {                                              \
        const int kk_ = (ti) * 32;                                       \
        gload_lds16(A + ar0 + kk_, (char*)&As[buf][0] + ls0);            \
        gload_lds16(A + ar1 + kk_, (char*)&As[buf][0] + ls1);            \
        gload_lds16(Bw + br0 + kk_, (char*)&Bs[buf][0] + ls0);           \
        gload_lds16(Bw + br1 + kk_, (char*)&Bs[buf][0] + ls1);           \
    } while (0)

    STAGE(0, 0);
    STAGE(1, 1);

#pragma unroll
    for (int t = 0; t < 12; ++t) {
        if (t < 11) asm volatile("s_waitcnt vmcnt(4)" ::: "memory");
        else        asm volatile("s_waitcnt vmcnt(0)" ::: "memory");
        __builtin_amdgcn_s_barrier();
        if (t + 2 < 12) STAGE(t + 2, (t + 2) % 3);
        const int cur = t % 3;
        bf16x8 af[4], bfr[4];
#pragma unroll
        for (int m = 0; m < 4; ++m) {
            const int row = wr + m * 16 + fr;
            af[m] = *(const bf16x8*)&As[cur][row * 32 + (fq ^ ((row >> 1) & 3)) * 8];
        }
#pragma unroll
        for (int n = 0; n < 4; ++n) {
            const int row = wc + n * 16 + fr;
            bfr[n] = *(const bf16x8*)&Bs[cur][row * 32 + (fq ^ ((row >> 1) & 3)) * 8];
        }
#pragma unroll
        for (int m = 0; m < 4; ++m)
#pragma unroll
            for (int n = 0; n < 4; ++n)
                acc[m][n] = __builtin_amdgcn_mfma_f32_16x16x32_bf16(af[m], bfr[n], acc[m][n], 0, 0, 0);
    }
#undef STAGE

    if (MODE == 0) {
        const int colbase = gy * 128;
        const int part = colbase / CDIM;              // uniform per block
        const int pcolbase = colbase - part * CDIM;
#pragma unroll
        for (int m = 0; m < 4; ++m) {
#pragma unroll
            for (int r = 0; r < 4; ++r) {
                const int row = gx * 128 + wr + m * 16 + fq * 4 + r;
                __bf16* orow = qkvout + (size_t)row * QKVROW + colbase + wc;
#pragma unroll
                for (int n = 0; n < 4; ++n) {
                    const int pcol = pcolbase + wc + n * 16 + fr;
                    float val = acc[m][n][r];
                    if (part == 0) val += qbias[pcol];
                    if (part == 2) val += vbias[pcol];
                    orow[n * 16 + fr] = (__bf16)val;
                }
            }
        }
    } else {
#pragma unroll
        for (int m = 0; m < 4; ++m) {
#pragma unroll
            for (int r = 0; r < 4; ++r) {
                const int row = gx * 128 + wr + m * 16 + fq * 4 + r;
                float* orow = fout + (size_t)row * CDIM + gy * 128 + wc;
#pragma unroll
                for (int n = 0; n < 4; ++n) {
                    const int col = gy * 128 + wc + n * 16 + fr;
                    orow[n * 16 + fr] = acc[m][n][r] + fbias[col];
                }
            }
        }
    }
}

// ---------------- attention: MFMA, one (b,h) per wave; qkv read from FLAT layout ----------------
#define WREG 15872
__global__ __launch_bounds__(256) void attn2(
    const __bf16* __restrict__ qkv, const float* __restrict__ maskT,
    const float* __restrict__ rpbT, const float* __restrict__ lscale,
    __bf16* __restrict__ aout)
{
    __shared__ char smem[4 * WREG];
    const int tid = threadIdx.x;
    const int wid = tid >> 6, lane = tid & 63;
    const int bh = blockIdx.x * 4 + wid;
    const int b = bh / NH, h = bh - b * NH;
    const int w = b & (NWIN - 1);
    const int c = lane & 15, g = lane >> 4;

    char* base = smem + wid * WREG;
    __bf16* Kl = (__bf16*)base;
    __bf16* Ql = (__bf16*)(base + 5120);
    __bf16* Vl = (__bf16*)(base + 10240);
    float* invq = (float*)(base + 15360);
    float* invk = (float*)(base + 15616);
    char* Pl = base;

    const float sc = __expf(fminf(lscale[h], 4.6051702f));

    {
        const int row = lane;
        // flat layout: token row = b*49+row, cols h*32 + part*384
        const size_t rb = ((size_t)b * NTOK + row) * QKVROW + h * HD;
        bf16x8 z;
#pragma unroll
        for (int e = 0; e < 8; ++e) z[e] = (__bf16)0.f;
        {
            bf16x8 t[4];
            float ss = 0.f;
            if (row < NTOK) {
#pragma unroll
                for (int ch = 0; ch < 4; ++ch) {
                    t[ch] = *(const bf16x8*)(qkv + rb + ch * 8);
#pragma unroll
                    for (int e = 0; e < 8; ++e) { float f = (float)t[ch][e]; ss += f * f; }
                }
            } else {
#pragma unroll
                for (int ch = 0; ch < 4; ++ch) t[ch] = z;
            }
#pragma unroll
            for (int ch = 0; ch < 4; ++ch) *(bf16x8*)&Ql[row * 40 + ch * 8] = t[ch];
            invq[row] = sc / fmaxf(sqrtf(ss), 1e-12f);
        }
        {
            bf16x8 t[4];
            float ss = 0.f;
            if (row < NTOK) {
#pragma unroll
                for (int ch = 0; ch < 4; ++ch) {
                    t[ch] = *(const bf16x8*)(qkv + rb + CDIM + ch * 8);
#pragma unroll
                    for (int e = 0; e < 8; ++e) { float f = (float)t[ch][e]; ss += f * f; }
                }
            } else {
#pragma unroll
                for (int ch = 0; ch < 4; ++ch) t[ch] = z;
            }
#pragma unroll
            for (int ch = 0; ch < 4; ++ch) *(bf16x8*)&Kl[row * 40 + ch * 8] = t[ch];
            invk[row] = 1.f / fmaxf(sqrtf(ss), 1e-12f);
        }
        {
            bf16x8 t[4];
            if (row < NTOK) {
#pragma unroll
                for (int ch = 0; ch < 4; ++ch) t[ch] = *(const bf16x8*)(qkv + rb + 2 * CDIM + ch * 8);
            } else {
#pragma unroll
                for (int ch = 0; ch < 4; ++ch) t[ch] = z;
            }
#pragma unroll
            for (int ch = 0; ch < 4; ++ch) *(bf16x8*)&Vl[row * 40 + ch * 8] = t[ch];
        }
    }

    bf16x8 kfr[4], qfr[4];
#pragma unroll
    for (int mt = 0; mt < 4; ++mt) kfr[mt] = *(const bf16x8*)&Kl[(mt * 16 + c) * 40 + g * 8];
#pragma unroll
    for (int nt = 0; nt < 4; ++nt) qfr[nt] = *(const bf16x8*)&Ql[(nt * 16 + c) * 40 + g * 8];
    f32x4 S[4][4];
#pragma unroll
    for (int mt = 0; mt < 4; ++mt)
#pragma unroll
        for (int nt = 0; nt < 4; ++nt) {
            S[mt][nt] = (f32x4){0.f, 0.f, 0.f, 0.f};
            S[mt][nt] = __builtin_amdgcn_mfma_f32_16x16x32_bf16(kfr[mt], qfr[nt], S[mt][nt], 0, 0, 0);
        }

    const float* rp = rpbT + h * (NTOK * NTOK);
    const float* mk = maskT + w * (NTOK * NTOK);
    float ivq[4];
#pragma unroll
    for (int nt = 0; nt < 4; ++nt) ivq[nt] = invq[nt * 16 + c];
#pragma unroll
    for (int mt = 0; mt < 4; ++mt) {
#pragma unroll
        for (int r = 0; r < 4; ++r) {
            const int k = mt * 16 + g * 4 + r;
            const float ivk = invk[k];
#pragma unroll
            for (int nt = 0; nt < 4; ++nt) {
                const int q = nt * 16 + c;
                float v = S[mt][nt][r] * ivk * ivq[nt];
                if (k < NTOK) {
                    if (q < NTOK) v += rp[k * NTOK + q] + mk[k * NTOK + q];
                } else {
                    v = -1e30f;
                }
                S[mt][nt][r] = v;
            }
        }
    }

    float rs[4];
#pragma unroll
    for (int nt = 0; nt < 4; ++nt) {
        float m = -1e30f;
#pragma unroll
        for (int mt = 0; mt < 4; ++mt)
#pragma unroll
            for (int r = 0; r < 4; ++r) m = fmaxf(m, S[mt][nt][r]);
        m = fmaxf(m, __shfl_xor(m, 16));
        m = fmaxf(m, __shfl_xor(m, 32));
        float s = 0.f;
#pragma unroll
        for (int mt = 0; mt < 4; ++mt)
#pragma unroll
            for (int r = 0; r < 4; ++r) {
                float e = __expf(S[mt][nt][r] - m);
                S[mt][nt][r] = e;
                s += e;
            }
        s += __shfl_xor(s, 16);
        s += __shfl_xor(s, 32);
        rs[nt] = 1.f / s;
    }

#pragma unroll
    for (int mt = 0; mt < 4; ++mt)
#pragma unroll
        for (int nt = 0; nt < 4; ++nt) {
            bf16x4 pk;
#pragma unroll
            for (int r = 0; r < 4; ++r) pk[r] = (__bf16)(S[mt][nt][r] * rs[nt]);
            *(bf16x4*)(Pl + (nt * 16 + c) * 144 + (mt * 16 + g * 4) * 2) = pk;
        }

    bf16x8 vfr[2][2];
#pragma unroll
    for (int kt = 0; kt < 2; ++kt)
#pragma unroll
        for (int dt = 0; dt < 2; ++dt) {
            bf16x8 t;
#pragma unroll
            for (int e = 0; e < 8; ++e) t[e] = Vl[(kt * 32 + g * 8 + e) * 40 + dt * 16 + c];
            vfr[kt][dt] = t;
        }
    f32x4 O[4][2];
#pragma unroll
    for (int mt = 0; mt < 4; ++mt)
#pragma unroll
        for (int dt = 0; dt < 2; ++dt) O[mt][dt] = (f32x4){0.f, 0.f, 0.f, 0.f};
#pragma unroll
    for (int mt = 0; mt < 4; ++mt)
#pragma unroll
        for (int kt = 0; kt < 2; ++kt) {
            bf16x8 pfr = *(const bf16x8*)(Pl + (mt * 16 + c) * 144 + kt * 64 + g * 16);
#pragma unroll
            for (int dt = 0; dt < 2; ++dt)
                O[mt][dt] = __builtin_amdgcn_mfma_f32_16x16x32_bf16(pfr, vfr[kt][dt], O[mt][dt], 0, 0, 0);
        }

#pragma unroll
    for (int mt = 0; mt < 4; ++mt)
#pragma unroll
        for (int r = 0; r < 4; ++r) {
            const int q = mt * 16 + g * 4 + r;
            if (q < NTOK) {
                const size_t off = ((size_t)b * NTOK + q) * CDIM + h * HD;
                aout[off + c] = (__bf16)O[mt][0][r];
                aout[off + 16 + c] = (__bf16)O[mt][1][r];
            }
        }
}

extern "C" void kernel_launch(void* const* d_in, const int* in_sizes, int n_in,
                              void* d_out, int out_size, void* d_ws, size_t ws_size,
                              hipStream_t stream) {
    const float* x      = (const float*)d_in[0];
    const float* mask   = (const float*)d_in[1];
    const float* qkv_w  = (const float*)d_in[2];
    const float* q_bias = (const float*)d_in[3];
    const float* v_bias = (const float*)d_in[4];
    const float* lscale = (const float*)d_in[5];
    const float* cpb_w1 = (const float*)d_in[6];
    const float* cpb_b1 = (const float*)d_in[7];
    const float* cpb_w2 = (const float*)d_in[8];
    const float* proj_w = (const float*)d_in[9];
    const float* proj_b = (const float*)d_in[10];
    float* out = (float*)d_out;

    const size_t NROWS = (size_t)BWIN * NTOK;           // 100352
    __bf16* qkvbuf  = (__bf16*)d_ws;                    // flat [100352][1152]
    __bf16* xbf     = qkvbuf + NROWS * QKVROW;          // x bf16, later reused as attn out
    __bf16* aoutbuf = xbf;                              // alias: lifetimes disjoint
    __bf16* qkv_wb  = xbf + NROWS * CDIM;
    __bf16* proj_wb = qkv_wb + QKVROW * CDIM;
    float*  bias_tab = (float*)(proj_wb + CDIM * CDIM);
    float*  rpbT   = bias_tab + 169 * NH;
    float*  maskT  = rpbT + NH * NTOK * NTOK;

    hipLaunchKernelGGL(cvt_f32_bf16, dim3((int)((NROWS * CDIM / 8 + 255) / 256)), dim3(256), 0, stream,
                       x, xbf, (int)(NROWS * CDIM / 8));
    hipLaunchKernelGGL(cvt_f32_bf16, dim3((QKVROW * CDIM / 8 + 255) / 256), dim3(256), 0, stream,
                       qkv_w, qkv_wb, QKVROW * CDIM / 8);
    hipLaunchKernelGGL(cvt_f32_bf16, dim3((CDIM * CDIM / 8 + 255) / 256), dim3(256), 0, stream,
                       proj_w, proj_wb, CDIM * CDIM / 8);
    hipLaunchKernelGGL(cpb_mlp_kernel, dim3(8), dim3(256), 0, stream,
                       cpb_w1, cpb_b1, cpb_w2, bias_tab);
    hipLaunchKernelGGL(rpbT_kernel, dim3((NH * NTOK * NTOK + 255) / 256), dim3(256), 0, stream,
                       bias_tab, rpbT);
    hipLaunchKernelGGL(maskT_kernel, dim3((NWIN * NTOK * NTOK + 255) / 256), dim3(256), 0, stream,
                       mask, maskT);
    hipLaunchKernelGGL((gemm6<0, 9>), dim3(784 * 9), dim3(256), 0, stream,
                       xbf, qkv_wb, q_bias, v_bias, qkvbuf, (float*)nullptr,
                       (const float*)nullptr);
    hipLaunchKernelGGL(attn2, dim3(BWIN * NH / 4), dim3(256), 0, stream,
                       qkvbuf, maskT, rpbT, lscale, aoutbuf);
    hipLaunchKernelGGL((gemm6<1, 3>), dim3(784 * 3), dim3(256), 0, stream,
                       aoutbuf, proj_wb, (const float*)nullptr, (const float*)nullptr,
                       (__bf16*)nullptr, out, proj_b);
}